// Round 5
// baseline (119.065 us; speedup 1.0000x reference)
//
#include <hip/hip_runtime.h>
#include <stdint.h>

typedef float f32x4 __attribute__((ext_vector_type(4)));
typedef __bf16 bf16x8 __attribute__((ext_vector_type(8)));

union Frag {
    bf16x8 v;
    uint32_t u[4];
    __bf16 e[8];
    uint4 q;
};

constexpr int B_ = 2, S_ = 2048, D_ = 1024, H_ = 16, HD_ = 64;
constexpr int M_ = B_ * S_;

// pi-permutation within each 32-element k-block: kl = 16*hi + 4*g + r  ->  8*g + 4*hi + r
// Applied identically to BOTH operands of every MFMA, so results are unchanged while each
// lane's 8 fragment elements {4g..4g+3, 16+4g..16+4g+3} become one contiguous 16B chunk.
__host__ __device__ constexpr int kperm(int kl) {
    return ((kl & 12) << 1) | ((kl & 16) >> 2) | (kl & 3);
}

typedef const __attribute__((address_space(1))) char gch_t;
typedef __attribute__((address_space(3))) char lch_t;
#define GLD(g, l) __builtin_amdgcn_global_load_lds((gch_t*)(g), (lch_t*)(l), 16, 0, 0)

#define MFMA16(a, b, c) __builtin_amdgcn_mfma_f32_16x16x32_bf16((a), (b), (c), 0, 0, 0)

// ---------------- kernel 0: cast x fp32 -> bf16, pi-permuted k ----------------
__global__ void k_cast_x(const float* __restrict__ x, __bf16* __restrict__ xb) {
    int t = blockIdx.x * 256 + threadIdx.x;       // one 32-element k-block per thread
    const float4* src = (const float4*)(x + (size_t)t * 32);
    __bf16 buf[32];
#pragma unroll
    for (int j = 0; j < 8; ++j) {
        float4 f = src[j];
        buf[kperm(4 * j + 0)] = (__bf16)f.x;
        buf[kperm(4 * j + 1)] = (__bf16)f.y;
        buf[kperm(4 * j + 2)] = (__bf16)f.z;
        buf[kperm(4 * j + 3)] = (__bf16)f.w;
    }
    uint4* dst = (uint4*)(xb + (size_t)t * 32);
#pragma unroll
    for (int j = 0; j < 4; ++j) dst[j] = ((const uint4*)buf)[j];
}

// ---------------- kernel 1: W -> Wt transposed bf16, pi-permuted k ----------------
__global__ void k_prep_w(const float* __restrict__ Wq, const float* __restrict__ Wk,
                         const float* __restrict__ Wv, __bf16* __restrict__ Wt) {
    __shared__ float tile[32][33];
    int p = blockIdx.z;
    const float* W = (p == 0) ? Wq : (p == 1 ? Wk : Wv);
    int n0 = blockIdx.x * 32, k0 = blockIdx.y * 32;
    int tx = threadIdx.x, ty = threadIdx.y;
#pragma unroll
    for (int t = 0; t < 4; ++t)
        tile[ty + 8 * t][tx] = W[(size_t)(k0 + ty + 8 * t) * D_ + n0 + tx];
    __syncthreads();
#pragma unroll
    for (int t = 0; t < 4; ++t)
        Wt[(size_t)(p * D_ + n0 + ty + 8 * t) * D_ + k0 + kperm(tx)] = (__bf16)tile[tx][ty + 8 * t];
}

// ---------------- kernel 2: fused QKV GEMM (m97 structure) ----------------
// 128x128 tile, BK=64, global_load_lds staging, swizzled ds_read_b128 fragments.
__global__ __launch_bounds__(256) void k_qkv(
        const __bf16* __restrict__ xb, const __bf16* __restrict__ Wt,
        const float* __restrict__ bq, const float* __restrict__ bk, const float* __restrict__ bv,
        __bf16* __restrict__ Qb, __bf16* __restrict__ Kb, __bf16* __restrict__ Vt) {
    __shared__ __align__(16) char ldsA[128 * 128];
    __shared__ __align__(16) char ldsB[128 * 128];

    const int tid = threadIdx.x;
    const int m0 = blockIdx.x * 128, n0 = blockIdx.y * 128;
    const int lane = tid & 63, w = tid >> 6;
    const int wr = w >> 1, wc = w & 1;
    const int g = lane >> 4, qr = lane & 15, qr7 = qr & 7;
    const int lr = lane >> 3, lp = lane & 7;
    const int c = lp ^ lr;   // logical chunk this lane stages (inverse of read swizzle)

    // staging sources: row = w*32 + j*8 + lr, chunk c; LDS dest linear (lane*16)
    const __bf16* aSrc = xb + (size_t)(m0 + w * 32 + lr) * D_ + c * 8;
    const __bf16* bSrc = Wt + (size_t)(n0 + w * 32 + lr) * D_ + c * 8;
    char* aDst = ldsA + (w * 32) * 128;
    char* bDst = ldsB + (w * 32) * 128;

    f32x4 acc[4][4] = {};

    for (int kk = 0; kk < D_; kk += 64) {
#pragma unroll
        for (int j = 0; j < 4; ++j) {
            GLD(aSrc + kk + j * (8 * D_), aDst + j * (8 * 128));
            GLD(bSrc + kk + j * (8 * D_), bDst + j * (8 * 128));
        }
        __syncthreads();

#pragma unroll
        for (int kc = 0; kc < 2; ++kc) {
            Frag afr[4], bfr[4];
#pragma unroll
            for (int mi = 0; mi < 4; ++mi) {
                int r = wr * 64 + mi * 16 + qr;
                afr[mi].q = *(const uint4*)(ldsA + r * 128 + (((4 * kc + g) ^ qr7) << 4));
            }
#pragma unroll
            for (int ni = 0; ni < 4; ++ni) {
                int r = wc * 64 + ni * 16 + qr;
                bfr[ni].q = *(const uint4*)(ldsB + r * 128 + (((4 * kc + g) ^ qr7) << 4));
            }
#pragma unroll
            for (int mi = 0; mi < 4; ++mi)
#pragma unroll
                for (int ni = 0; ni < 4; ++ni)
                    acc[mi][ni] = MFMA16(afr[mi].v, bfr[ni].v, acc[mi][ni]);
        }
        __syncthreads();
    }

    // epilogue: bias, Q-scale, scatter into pi-permuted Qb/Kb + Vt (kv-permuted)
    const int p = n0 >> 10;
    const float* bias = (p == 0) ? bq : (p == 1 ? bk : bv);
#pragma unroll
    for (int ni = 0; ni < 4; ++ni) {
        int n = n0 + wc * 64 + ni * 16 + qr;
        int d = n & 1023;
        float bb = bias[d];
        int h = d >> 6, hd = d & 63;
        int hd_s = (hd & 32) | kperm(hd & 31);
#pragma unroll
        for (int mi = 0; mi < 4; ++mi) {
#pragma unroll
            for (int r = 0; r < 4; ++r) {
                int m = m0 + wr * 64 + mi * 16 + 4 * g + r;
                float vv = acc[mi][ni][r] + bb;
                int b = m >> 11, s = m & 2047;
                if (p == 0) {
                    vv *= 0.125f;   // 1/sqrt(HD), exact power of 2
                    Qb[((size_t)((b * H_ + h) * S_ + s)) * HD_ + hd_s] = (__bf16)vv;
                } else if (p == 1) {
                    Kb[((size_t)((b * H_ + h) * S_ + s)) * HD_ + hd_s] = (__bf16)vv;
                } else {
                    int s_s = (s & ~31) | kperm(s & 31);
                    Vt[((size_t)((b * H_ + h) * HD_ + hd)) * S_ + s_s] = (__bf16)vv;
                }
            }
        }
    }
}

// ---------------- kernel 3: flash attention + residual ----------------
__global__ __launch_bounds__(256) void k_attn(
        const __bf16* __restrict__ Qb, const __bf16* __restrict__ Kb,
        const __bf16* __restrict__ Vt, const float* __restrict__ x,
        float* __restrict__ out) {
    __shared__ __align__(16) char ldsK[64 * 128];   // [kv][hd] bf16, swizzled chunks
    __shared__ __align__(16) char ldsV[64 * 128];   // [hd][kv] bf16, swizzled chunks

    const int tid = threadIdx.x;
    const int q0 = blockIdx.x * 64;
    const int bh = blockIdx.y;
    const int lane = tid & 63, w = tid >> 6;
    const int g = lane >> 4, qr = lane & 15, qr7 = qr & 7;
    const int lr = lane >> 3, lp = lane & 7;
    const int c = lp ^ lr;
    const int qrow = q0 + w * 16 + qr;

    // Q fragments (B-operand of swapped QK^T), pi-stored so each is one contiguous 16B
    Frag qf[2];
    const __bf16* qp = Qb + ((size_t)bh * S_ + qrow) * HD_;
    qf[0].q = *(const uint4*)(qp + g * 8);
    qf[1].q = *(const uint4*)(qp + 32 + g * 8);

    const __bf16* kSrc = Kb + ((size_t)bh * S_ + w * 16 + lr) * HD_ + c * 8;
    const __bf16* vSrc = Vt + ((size_t)bh * HD_ + w * 16 + lr) * S_ + c * 8;
    char* kDst = ldsK + (w * 16) * 128;
    char* vDst = ldsV + (w * 16) * 128;

    f32x4 oacc[4] = {};
    f32x4 lacc = {};
    float mrun = -INFINITY;
    const float L2E = 1.44269504f;
    const float THR = 5.545177f;    // 8*ln2 -> P bounded by 256, bf16-safe

    Frag ones;
    ones.u[0] = ones.u[1] = ones.u[2] = ones.u[3] = 0x3f803f80u;  // bf16 1.0 pairs

    for (int kv0 = 0; kv0 < S_; kv0 += 64) {
        GLD(kSrc + (size_t)kv0 * HD_,            kDst);
        GLD(kSrc + (size_t)kv0 * HD_ + 8 * HD_,  kDst + 8 * 128);
        GLD(vSrc + kv0,                          vDst);
        GLD(vSrc + kv0 + 8 * S_,                 vDst + 8 * 128);
        __syncthreads();

        // swapped QK^T: S^T[kv][q] tiles
        f32x4 sc[4];
#pragma unroll
        for (int kt = 0; kt < 4; ++kt) {
            const char* base = ldsK + (kt * 16 + qr) * 128;
            Frag k0, k1;
            k0.q = *(const uint4*)(base + ((g ^ qr7) << 4));
            k1.q = *(const uint4*)(base + (((4 + g) ^ qr7) << 4));
            f32x4 z = {};
            z = MFMA16(k0.v, qf[0].v, z);
            z = MFMA16(k1.v, qf[1].v, z);
            sc[kt] = z;
        }

        // online softmax with defer-max (T13)
        float tmax = -INFINITY;
#pragma unroll
        for (int kt = 0; kt < 4; ++kt)
#pragma unroll
            for (int r = 0; r < 4; ++r) tmax = fmaxf(tmax, sc[kt][r]);
        tmax = fmaxf(tmax, __shfl_xor(tmax, 16, 64));
        tmax = fmaxf(tmax, __shfl_xor(tmax, 32, 64));

        if (__any(tmax > mrun + THR)) {
            float mnew = fmaxf(mrun, tmax);
            float scale = __builtin_amdgcn_exp2f((mrun - mnew) * L2E);
            mrun = mnew;
            float scr[4];
#pragma unroll
            for (int r = 0; r < 4; ++r) scr[r] = __shfl(scale, (lane & 48) | (4 * g + r), 64);
#pragma unroll
            for (int ni = 0; ni < 4; ++ni)
#pragma unroll
                for (int r = 0; r < 4; ++r) oacc[ni][r] *= scr[r];
#pragma unroll
            for (int r = 0; r < 4; ++r) lacc[r] *= scr[r];
        }

        // P = exp2(s*log2e - m*log2e), packed straight into A-fragments
        float m2 = mrun * L2E;
        Frag pa[2];
#pragma unroll
        for (int r = 0; r < 4; ++r) {
            pa[0].e[r]     = (__bf16)__builtin_amdgcn_exp2f(fmaf(sc[0][r], L2E, -m2));
            pa[0].e[4 + r] = (__bf16)__builtin_amdgcn_exp2f(fmaf(sc[1][r], L2E, -m2));
            pa[1].e[r]     = (__bf16)__builtin_amdgcn_exp2f(fmaf(sc[2][r], L2E, -m2));
            pa[1].e[4 + r] = (__bf16)__builtin_amdgcn_exp2f(fmaf(sc[3][r], L2E, -m2));
        }

        // row-sums via MFMA against ones (l lands directly in C/D layout)
        lacc = MFMA16(pa[0].v, ones.v, lacc);
        lacc = MFMA16(pa[1].v, ones.v, lacc);

        // PV
#pragma unroll
        for (int ni = 0; ni < 4; ++ni) {
            const char* base = ldsV + (ni * 16 + qr) * 128;
            Frag v0, v1;
            v0.q = *(const uint4*)(base + ((g ^ qr7) << 4));
            v1.q = *(const uint4*)(base + (((4 + g) ^ qr7) << 4));
            oacc[ni] = MFMA16(pa[0].v, v0.v, oacc[ni]);
            oacc[ni] = MFMA16(pa[1].v, v1.v, oacc[ni]);
        }
        __syncthreads();
    }

    // finalize: normalize (l already per-row in C/D layout), residual, store
    float rs[4];
#pragma unroll
    for (int r = 0; r < 4; ++r) rs[r] = 1.0f / lacc[r];

    int b = bh >> 4, h = bh & 15;
#pragma unroll
    for (int ni = 0; ni < 4; ++ni) {
#pragma unroll
        for (int r = 0; r < 4; ++r) {
            int q = q0 + w * 16 + 4 * g + r;
            size_t addr = ((size_t)(b * S_ + q)) * D_ + h * 64 + ni * 16 + qr;
            out[addr] = oacc[ni][r] * rs[r] + x[addr];
        }
    }
}

// ---------------- launch ----------------
extern "C" void kernel_launch(void* const* d_in, const int* in_sizes, int n_in,
                              void* d_out, int out_size, void* d_ws, size_t ws_size,
                              hipStream_t stream) {
    const float* x  = (const float*)d_in[0];
    const float* Wq = (const float*)d_in[1];
    const float* bq = (const float*)d_in[2];
    const float* Wk = (const float*)d_in[3];
    const float* bk = (const float*)d_in[4];
    const float* Wv = (const float*)d_in[5];
    const float* bv = (const float*)d_in[6];
    float* out = (float*)d_out;

    char* ws = (char*)d_ws;
    __bf16* xb = (__bf16*)(ws);                         // 4096x1024 bf16   = 8 MB
    __bf16* Wt = (__bf16*)(ws + 8388608);               // 3072x1024 bf16   = 6 MB
    __bf16* Qb = (__bf16*)(ws + 14680064);              // [b,h,s,hd] bf16  = 8 MB
    __bf16* Kb = (__bf16*)(ws + 23068672);              // [b,h,s,hd] bf16  = 8 MB
    __bf16* Vt = (__bf16*)(ws + 31457280);              // [b,h,hd,s] bf16  = 8 MB

    k_cast_x<<<512, 256, 0, stream>>>(x, xb);
    k_prep_w<<<dim3(32, 32, 3), dim3(32, 8), 0, stream>>>(Wq, Wk, Wv, Wt);
    k_qkv<<<dim3(32, 24), 256, 0, stream>>>(xb, Wt, bq, bk, bv, Qb, Kb, Vt);
    k_attn<<<dim3(32, 32), 256, 0, stream>>>(Qb, Kb, Vt, x, out);
}

// Round 6
// 117.976 us; speedup vs baseline: 1.0092x; 1.0092x over previous
//
#include <hip/hip_runtime.h>
#include <stdint.h>

typedef float f32x4 __attribute__((ext_vector_type(4)));
typedef __bf16 bf16x8 __attribute__((ext_vector_type(8)));

union Frag {
    bf16x8 v;
    uint32_t u[4];
    __bf16 e[8];
    uint4 q;
};

constexpr int B_ = 2, S_ = 2048, D_ = 1024, H_ = 16, HD_ = 64;
constexpr int M_ = B_ * S_;

// pi-permutation within each 32-element k-block: kl = 16*hi + 4*g + r  ->  8*g + 4*hi + r
// Applied identically to BOTH operands of every MFMA, so results are unchanged while each
// lane's 8 fragment elements become one contiguous 16B chunk.
__host__ __device__ constexpr int kperm(int kl) {
    return ((kl & 12) << 1) | ((kl & 16) >> 2) | (kl & 3);
}

typedef const __attribute__((address_space(1))) char gch_t;
typedef __attribute__((address_space(3))) char lch_t;
#define GLD(g, l) __builtin_amdgcn_global_load_lds((gch_t*)(g), (lch_t*)(l), 16, 0, 0)

#define MFMA16(a, b, c) __builtin_amdgcn_mfma_f32_16x16x32_bf16((a), (b), (c), 0, 0, 0)

// ---------------- kernel 0: cast x fp32 -> bf16, pi-permuted k ----------------
__global__ void k_cast_x(const float* __restrict__ x, __bf16* __restrict__ xb) {
    int t = blockIdx.x * 256 + threadIdx.x;
    const float4* src = (const float4*)(x + (size_t)t * 32);
    __bf16 buf[32];
#pragma unroll
    for (int j = 0; j < 8; ++j) {
        float4 f = src[j];
        buf[kperm(4 * j + 0)] = (__bf16)f.x;
        buf[kperm(4 * j + 1)] = (__bf16)f.y;
        buf[kperm(4 * j + 2)] = (__bf16)f.z;
        buf[kperm(4 * j + 3)] = (__bf16)f.w;
    }
    uint4* dst = (uint4*)(xb + (size_t)t * 32);
#pragma unroll
    for (int j = 0; j < 4; ++j) dst[j] = ((const uint4*)buf)[j];
}

// ---------------- kernel 1: W -> Wt transposed bf16, pi-permuted k ----------------
__global__ void k_prep_w(const float* __restrict__ Wq, const float* __restrict__ Wk,
                         const float* __restrict__ Wv, __bf16* __restrict__ Wt) {
    __shared__ float tile[32][33];
    int p = blockIdx.z;
    const float* W = (p == 0) ? Wq : (p == 1 ? Wk : Wv);
    int n0 = blockIdx.x * 32, k0 = blockIdx.y * 32;
    int tx = threadIdx.x, ty = threadIdx.y;
#pragma unroll
    for (int t = 0; t < 4; ++t)
        tile[ty + 8 * t][tx] = W[(size_t)(k0 + ty + 8 * t) * D_ + n0 + tx];
    __syncthreads();
#pragma unroll
    for (int t = 0; t < 4; ++t)
        Wt[(size_t)(p * D_ + n0 + ty + 8 * t) * D_ + k0 + kperm(tx)] = (__bf16)tile[tx][ty + 8 * t];
}

// ---------------- kernel 2: fused QKV GEMM, 2-phase double-buffered ----------------
// 128x128 tile, BK=64. STAGE(t+1) issued BEFORE COMPUTE(t); single barrier per tile
// (its implicit vmcnt(0) drain lands AFTER the compute, so the load latency hides).
__global__ __launch_bounds__(256) void k_qkv(
        const __bf16* __restrict__ xb, const __bf16* __restrict__ Wt,
        const float* __restrict__ bq, const float* __restrict__ bk, const float* __restrict__ bv,
        __bf16* __restrict__ Qb, __bf16* __restrict__ Kb, __bf16* __restrict__ Vt) {
    __shared__ __align__(16) char ldsA[2][128 * 128];
    __shared__ __align__(16) char ldsB[2][128 * 128];

    const int tid = threadIdx.x;
    const int m0 = blockIdx.x * 128, n0 = blockIdx.y * 128;
    const int lane = tid & 63, w = tid >> 6;
    const int wr = w >> 1, wc = w & 1;
    const int g = lane >> 4, qr = lane & 15, qr7 = qr & 7;
    const int lr = lane >> 3, lp = lane & 7;
    const int c = lp ^ lr;   // staged chunk = inverse of read swizzle

    const __bf16* aSrc = xb + (size_t)(m0 + w * 32 + lr) * D_ + c * 8;
    const __bf16* bSrc = Wt + (size_t)(n0 + w * 32 + lr) * D_ + c * 8;
    const int dstOff = (w * 32) * 128;

    f32x4 acc[4][4] = {};

    auto STAGE = [&](int buf, int kk) {
#pragma unroll
        for (int j = 0; j < 4; ++j) {
            GLD(aSrc + kk + j * (8 * D_), ldsA[buf] + dstOff + j * (8 * 128));
            GLD(bSrc + kk + j * (8 * D_), ldsB[buf] + dstOff + j * (8 * 128));
        }
    };
    auto COMPUTE = [&](int buf) {
#pragma unroll
        for (int kc = 0; kc < 2; ++kc) {
            Frag afr[4], bfr[4];
#pragma unroll
            for (int mi = 0; mi < 4; ++mi) {
                int r = wr * 64 + mi * 16 + qr;
                afr[mi].q = *(const uint4*)(ldsA[buf] + r * 128 + (((4 * kc + g) ^ qr7) << 4));
            }
#pragma unroll
            for (int ni = 0; ni < 4; ++ni) {
                int r = wc * 64 + ni * 16 + qr;
                bfr[ni].q = *(const uint4*)(ldsB[buf] + r * 128 + (((4 * kc + g) ^ qr7) << 4));
            }
#pragma unroll
            for (int mi = 0; mi < 4; ++mi)
#pragma unroll
                for (int ni = 0; ni < 4; ++ni)
                    acc[mi][ni] = MFMA16(afr[mi].v, bfr[ni].v, acc[mi][ni]);
        }
    };

    // 16 K-tiles (K=1024, BK=64); hand-paired so buffer index is compile-time static
    STAGE(0, 0);
    __syncthreads();
    for (int t = 0; t < 14; t += 2) {
        STAGE(1, (t + 1) * 64);
        COMPUTE(0);
        __syncthreads();
        STAGE(0, (t + 2) * 64);
        COMPUTE(1);
        __syncthreads();
    }
    STAGE(1, 15 * 64);
    COMPUTE(0);          // tile 14
    __syncthreads();
    COMPUTE(1);          // tile 15

    // epilogue: bias, Q-scale, scatter into pi-permuted Qb/Kb + Vt (kv-permuted)
    const int p = n0 >> 10;
    const float* bias = (p == 0) ? bq : (p == 1 ? bk : bv);
#pragma unroll
    for (int ni = 0; ni < 4; ++ni) {
        int n = n0 + wc * 64 + ni * 16 + qr;
        int d = n & 1023;
        float bb = bias[d];
        int h = d >> 6, hd = d & 63;
        int hd_s = (hd & 32) | kperm(hd & 31);
#pragma unroll
        for (int mi = 0; mi < 4; ++mi) {
#pragma unroll
            for (int r = 0; r < 4; ++r) {
                int m = m0 + wr * 64 + mi * 16 + 4 * g + r;
                float vv = acc[mi][ni][r] + bb;
                int b = m >> 11, s = m & 2047;
                if (p == 0) {
                    vv *= 0.125f;   // 1/sqrt(HD), exact power of 2
                    Qb[((size_t)((b * H_ + h) * S_ + s)) * HD_ + hd_s] = (__bf16)vv;
                } else if (p == 1) {
                    Kb[((size_t)((b * H_ + h) * S_ + s)) * HD_ + hd_s] = (__bf16)vv;
                } else {
                    int s_s = (s & ~31) | kperm(s & 31);
                    Vt[((size_t)((b * H_ + h) * HD_ + hd)) * S_ + s_s] = (__bf16)vv;
                }
            }
        }
    }
}

// ---------------- kernel 3: flash attention + residual, 2-phase double-buffered ----------------
__global__ __launch_bounds__(256) void k_attn(
        const __bf16* __restrict__ Qb, const __bf16* __restrict__ Kb,
        const __bf16* __restrict__ Vt, const float* __restrict__ x,
        float* __restrict__ out) {
    __shared__ __align__(16) char ldsK[2][64 * 128];   // [kv][hd] bf16, swizzled chunks
    __shared__ __align__(16) char ldsV[2][64 * 128];   // [hd][kv] bf16, swizzled chunks

    const int tid = threadIdx.x;
    const int q0 = blockIdx.x * 64;
    const int bh = blockIdx.y;
    const int lane = tid & 63, w = tid >> 6;
    const int g = lane >> 4, qr = lane & 15, qr7 = qr & 7;
    const int lr = lane >> 3, lp = lane & 7;
    const int c = lp ^ lr;
    const int qrow = q0 + w * 16 + qr;

    // Q fragments (B-operand of swapped QK^T), pi-stored: contiguous 16B each
    Frag qf[2];
    const __bf16* qp = Qb + ((size_t)bh * S_ + qrow) * HD_;
    qf[0].q = *(const uint4*)(qp + g * 8);
    qf[1].q = *(const uint4*)(qp + 32 + g * 8);

    const __bf16* kSrc = Kb + ((size_t)bh * S_ + w * 16 + lr) * HD_ + c * 8;
    const __bf16* vSrc = Vt + ((size_t)bh * HD_ + w * 16 + lr) * S_ + c * 8;
    const int dstOff = (w * 16) * 128;

    f32x4 oacc[4] = {};
    f32x4 lacc = {};
    float mrun = -INFINITY;
    const float L2E = 1.44269504f;
    const float THR = 5.545177f;    // 8*ln2 -> P bounded by 256, bf16-safe

    Frag ones;
    ones.u[0] = ones.u[1] = ones.u[2] = ones.u[3] = 0x3f803f80u;  // bf16 1.0 pairs

    auto STAGE = [&](int buf, int kv0) {
        GLD(kSrc + (size_t)kv0 * HD_,           ldsK[buf] + dstOff);
        GLD(kSrc + (size_t)kv0 * HD_ + 8 * HD_, ldsK[buf] + dstOff + 8 * 128);
        GLD(vSrc + kv0,                         ldsV[buf] + dstOff);
        GLD(vSrc + kv0 + 8 * S_,                ldsV[buf] + dstOff + 8 * 128);
    };

    auto TILE = [&](int buf) {
        // swapped QK^T: S^T[kv][q] tiles
        f32x4 sc[4];
        __builtin_amdgcn_s_setprio(1);
#pragma unroll
        for (int kt = 0; kt < 4; ++kt) {
            const char* base = ldsK[buf] + (kt * 16 + qr) * 128;
            Frag k0, k1;
            k0.q = *(const uint4*)(base + ((g ^ qr7) << 4));
            k1.q = *(const uint4*)(base + (((4 + g) ^ qr7) << 4));
            f32x4 z = {};
            z = MFMA16(k0.v, qf[0].v, z);
            z = MFMA16(k1.v, qf[1].v, z);
            sc[kt] = z;
        }
        __builtin_amdgcn_s_setprio(0);

        // online softmax with defer-max (T13)
        float tmax = -INFINITY;
#pragma unroll
        for (int kt = 0; kt < 4; ++kt)
#pragma unroll
            for (int r = 0; r < 4; ++r) tmax = fmaxf(tmax, sc[kt][r]);
        tmax = fmaxf(tmax, __shfl_xor(tmax, 16, 64));
        tmax = fmaxf(tmax, __shfl_xor(tmax, 32, 64));

        if (__any(tmax > mrun + THR)) {
            float mnew = fmaxf(mrun, tmax);
            float scale = __builtin_amdgcn_exp2f((mrun - mnew) * L2E);
            mrun = mnew;
            float scr[4];
#pragma unroll
            for (int r = 0; r < 4; ++r) scr[r] = __shfl(scale, (lane & 48) | (4 * g + r), 64);
#pragma unroll
            for (int ni = 0; ni < 4; ++ni)
#pragma unroll
                for (int r = 0; r < 4; ++r) oacc[ni][r] *= scr[r];
#pragma unroll
            for (int r = 0; r < 4; ++r) lacc[r] *= scr[r];
        }

        // P = exp2(s*log2e - m*log2e), packed straight into A-fragments
        float m2 = mrun * L2E;
        Frag pa[2];
#pragma unroll
        for (int r = 0; r < 4; ++r) {
            pa[0].e[r]     = (__bf16)__builtin_amdgcn_exp2f(fmaf(sc[0][r], L2E, -m2));
            pa[0].e[4 + r] = (__bf16)__builtin_amdgcn_exp2f(fmaf(sc[1][r], L2E, -m2));
            pa[1].e[r]     = (__bf16)__builtin_amdgcn_exp2f(fmaf(sc[2][r], L2E, -m2));
            pa[1].e[4 + r] = (__bf16)__builtin_amdgcn_exp2f(fmaf(sc[3][r], L2E, -m2));
        }

        __builtin_amdgcn_s_setprio(1);
        // row-sums via MFMA against ones (l lands directly in C/D layout)
        lacc = MFMA16(pa[0].v, ones.v, lacc);
        lacc = MFMA16(pa[1].v, ones.v, lacc);

        // PV
#pragma unroll
        for (int ni = 0; ni < 4; ++ni) {
            const char* base = ldsV[buf] + (ni * 16 + qr) * 128;
            Frag v0, v1;
            v0.q = *(const uint4*)(base + ((g ^ qr7) << 4));
            v1.q = *(const uint4*)(base + (((4 + g) ^ qr7) << 4));
            oacc[ni] = MFMA16(pa[0].v, v0.v, oacc[ni]);
            oacc[ni] = MFMA16(pa[1].v, v1.v, oacc[ni]);
        }
        __builtin_amdgcn_s_setprio(0);
    };

    // 32 kv-tiles, 2-phase double buffer, hand-paired for static buffer index
    STAGE(0, 0);
    __syncthreads();
    for (int t = 0; t < 30; t += 2) {
        STAGE(1, (t + 1) * 64);
        TILE(0);
        __syncthreads();
        STAGE(0, (t + 2) * 64);
        TILE(1);
        __syncthreads();
    }
    STAGE(1, 31 * 64);
    TILE(0);            // tile 30
    __syncthreads();
    TILE(1);            // tile 31

    // finalize: normalize (l already per-row in C/D layout), residual, store
    float rs[4];
#pragma unroll
    for (int r = 0; r < 4; ++r) rs[r] = 1.0f / lacc[r];

    int b = bh >> 4, h = bh & 15;
#pragma unroll
    for (int ni = 0; ni < 4; ++ni) {
#pragma unroll
        for (int r = 0; r < 4; ++r) {
            int q = q0 + w * 16 + 4 * g + r;
            size_t addr = ((size_t)(b * S_ + q)) * D_ + h * 64 + ni * 16 + qr;
            out[addr] = oacc[ni][r] * rs[r] + x[addr];
        }
    }
}

// ---------------- launch ----------------
extern "C" void kernel_launch(void* const* d_in, const int* in_sizes, int n_in,
                              void* d_out, int out_size, void* d_ws, size_t ws_size,
                              hipStream_t stream) {
    const float* x  = (const float*)d_in[0];
    const float* Wq = (const float*)d_in[1];
    const float* bq = (const float*)d_in[2];
    const float* Wk = (const float*)d_in[3];
    const float* bk = (const float*)d_in[4];
    const float* Wv = (const float*)d_in[5];
    const float* bv = (const float*)d_in[6];
    float* out = (float*)d_out;

    char* ws = (char*)d_ws;
    __bf16* xb = (__bf16*)(ws);                         // 4096x1024 bf16   = 8 MB
    __bf16* Wt = (__bf16*)(ws + 8388608);               // 3072x1024 bf16   = 6 MB
    __bf16* Qb = (__bf16*)(ws + 14680064);              // [b,h,s,hd] bf16  = 8 MB
    __bf16* Kb = (__bf16*)(ws + 23068672);              // [b,h,s,hd] bf16  = 8 MB
    __bf16* Vt = (__bf16*)(ws + 31457280);              // [b,h,hd,s] bf16  = 8 MB

    k_cast_x<<<512, 256, 0, stream>>>(x, xb);
    k_prep_w<<<dim3(32, 32, 3), dim3(32, 8), 0, stream>>>(Wq, Wk, Wv, Wt);
    k_qkv<<<dim3(32, 24), 256, 0, stream>>>(xb, Wt, bq, bk, bv, Qb, Kb, Vt);
    k_attn<<<dim3(32, 32), 256, 0, stream>>>(Qb, Kb, Vt, x, out);
}